// Round 14
// baseline (153.178 us; speedup 1.0000x reference)
//
#include <hip/hip_runtime.h>
#include <hip/hip_bf16.h>

#define D 128
#define NH 256
#define K1 384
#define BM 64
#define E_TOTAL 320000
#define NNODES 10000

typedef __attribute__((ext_vector_type(8))) short bf16x8;
typedef __attribute__((ext_vector_type(4))) float f32x4;

__device__ __forceinline__ unsigned short f2b(float f) {
  unsigned int u = __builtin_bit_cast(unsigned int, f);
  u += 0x7fffu + ((u >> 16) & 1u);   // round-to-nearest-even
  return (unsigned short)(u >> 16);
}

// nodes fp32 -> bf16 table
__global__ void cast_nodes_kernel(const float* __restrict__ nodes,
                                  ushort* __restrict__ out) {
  int i = (blockIdx.x * 256 + threadIdx.x) * 4;
  float4 v = *(const float4*)(nodes + i);
  ushort4 b;
  b.x = f2b(v.x); b.y = f2b(v.y); b.z = f2b(v.z); b.w = f2b(v.w);
  *(ushort4*)(out + i) = b;
}

// Pack W1 (fp32 [512][256], rows 0..383 used) into MFMA-fragment order:
// chunk c = nt*12 + ks ; lane l holds W1[ks*32+(l>>4)*8 + j][nt*16+(l&15)]
__global__ void pack_w1_kernel(const float* __restrict__ W1,
                               ushort* __restrict__ W1p) {
  int c = blockIdx.x * 256 + threadIdx.x;   // 12288 threads
  int nt = c / (12 * 64);
  int rem = c % (12 * 64);
  int ks = rem >> 6;
  int l = rem & 63;
  int col = nt * 16 + (l & 15);
  int k0 = ks * 32 + (l >> 4) * 8;
  ushort* dst = W1p + (size_t)c * 8;
  #pragma unroll
  for (int j = 0; j < 8; ++j)
    dst[j] = f2b(W1[(size_t)(k0 + j) * NH + col]);
}

// Pack W2 (fp32 [256][128]) same fragment order: chunk c = nt2*8 + ks
__global__ void pack_w2_kernel(const float* __restrict__ W2,
                               ushort* __restrict__ W2p) {
  int c = blockIdx.x * 256 + threadIdx.x;   // 4096 threads
  int nt2 = c / (8 * 64);
  int rem = c % (8 * 64);
  int ks = rem >> 6;
  int l = rem & 63;
  int col = nt2 * 16 + (l & 15);
  int k0 = ks * 32 + (l >> 4) * 8;
  ushort* dst = W2p + (size_t)c * 8;
  #pragma unroll
  for (int j = 0; j < 8; ++j)
    dst[j] = f2b(W2[(size_t)(k0 + j) * D + col]);
}

// cvec[n] = b1[n] + sum_k globals[k] * W1[384+k][n]
__global__ void cvec_kernel(const float* __restrict__ W1,
                            const float* __restrict__ b1,
                            const float* __restrict__ g,
                            float* __restrict__ cvec) {
  int n = threadIdx.x;  // 256
  float acc = b1[n];
  for (int k = 0; k < D; ++k)
    acc += g[k] * W1[(size_t)(K1 + k) * NH + n];
  cvec[n] = acc;
}

// 4 waves x 64-col panels: halves LDS A-read duplication vs 8x32 while
// keeping each weight panel read exactly once per block. Hs aliases Xs
// (48 KB LDS -> 3 blocks/CU, 12 waves).
__global__ __launch_bounds__(256, 3) void fused_kernel(
    const float* __restrict__ edges,
    const ushort* __restrict__ nodes_b,
    const int* __restrict__ receivers,
    const int* __restrict__ senders,
    const ushort* __restrict__ W1p,    // packed fragments, 16nt x 12ks x 64lane x 8
    const float* __restrict__ cvec,    // [256]
    const ushort* __restrict__ W2p,    // packed fragments, 8nt x 8ks x 64lane x 8
    const float* __restrict__ b2,      // [128]
    float* __restrict__ out) {
  __shared__ char Xs[BM * 768];   // 64 x 384 bf16, byte ^= (row&7)<<4 swizzle
  char* Hs = Xs;                  // 64 x 256 bf16 aliases Xs (double barrier)

  const int ebase = blockIdx.x * BM;
  const int tid = threadIdx.x;

  // ---- gather indices: thread covers rows rb, rb+16, rb+32, rb+48
  const int rb = tid >> 4;
  const int gc = (tid & 15) << 3;    // bf16 col chunk (16 B)
  int idxR[4], idxS[4];
  #pragma unroll
  for (int j = 0; j < 4; ++j) {
    idxR[j] = receivers[ebase + rb + j * 16];
    idxS[j] = senders[ebase + rb + j * 16];
  }

  // ---- edge loads: 8 float4 per thread (64 x 128 fp32)
  float4 ev[8];
  #pragma unroll
  for (int it = 0; it < 8; ++it) {
    int c = tid + it * 256;
    int row = c >> 5, colc = (c & 31) << 2;
    ev[it] = *(const float4*)(edges + (size_t)(ebase + row) * D + colc);
  }

  // ---- gathers: 8 uint4
  uint4 gvR[4], gvS[4];
  #pragma unroll
  for (int j = 0; j < 4; ++j) {
    gvR[j] = *(const uint4*)(nodes_b + (size_t)idxR[j] * D + gc);
    gvS[j] = *(const uint4*)(nodes_b + (size_t)idxS[j] * D + gc);
  }

  // ---- convert + LDS writes
  #pragma unroll
  for (int it = 0; it < 8; ++it) {
    int c = tid + it * 256;
    int row = c >> 5, colc = (c & 31) << 2;
    ushort4 b;
    b.x = f2b(ev[it].x); b.y = f2b(ev[it].y); b.z = f2b(ev[it].z); b.w = f2b(ev[it].w);
    *(ushort4*)(Xs + row * 768 + ((colc * 2) ^ ((row & 7) << 4))) = b;
  }
  {
    const int cR = (D + gc) * 2, cS = (2 * D + gc) * 2;
    #pragma unroll
    for (int j = 0; j < 4; ++j) {
      int row = rb + j * 16;
      int sw = (row & 7) << 4;
      *(uint4*)(Xs + row * 768 + (cR ^ sw)) = gvR[j];
      *(uint4*)(Xs + row * 768 + (cS ^ sw)) = gvS[j];
    }
  }
  __syncthreads();

  const int lane = tid & 63;
  const int wave = tid >> 6;     // 0..3; GEMM1 cols [64w,64w+64); GEMM2 cols [32w,32w+32)
  const int lr = lane & 15;
  const int kg = lane >> 4;

  // epilogue constants (latency hidden under GEMM1)
  float cv[4];
  #pragma unroll
  for (int n = 0; n < 4; ++n) cv[n] = cvec[wave * 64 + n * 16 + lr];
  float bias2[2];
  #pragma unroll
  for (int n = 0; n < 2; ++n) bias2[n] = b2[wave * 32 + n * 16 + lr];

  // ---- GEMM1: [64x384] @ [384x64-per-wave], packed-fragment B (1KB/instr)
  const ushort* w1base = W1p + (size_t)(wave * 4) * 12 * 512 + lane * 8;

  f32x4 acc[4][4] = {};
  bf16x8 bb[2][4];
  #pragma unroll
  for (int n = 0; n < 4; ++n)
    bb[0][n] = *(const bf16x8*)(w1base + (size_t)n * 12 * 512);

  #pragma unroll
  for (int ks = 0; ks < 12; ++ks) {
    const int cur = ks & 1, nxt = cur ^ 1;
    if (ks < 11) {
      #pragma unroll
      for (int n = 0; n < 4; ++n)
        bb[nxt][n] = *(const bf16x8*)(w1base + (size_t)n * 12 * 512 + (ks + 1) * 512);
    }
    const int k0 = ks * 32 + kg * 8;
    bf16x8 a[4];
    #pragma unroll
    for (int m = 0; m < 4; ++m) {
      int row = m * 16 + lr;
      a[m] = *(const bf16x8*)(Xs + row * 768 + ((k0 * 2) ^ ((row & 7) << 4)));
    }
    #pragma unroll
    for (int m = 0; m < 4; ++m)
      #pragma unroll
      for (int n = 0; n < 4; ++n)
        acc[m][n] = __builtin_amdgcn_mfma_f32_16x16x32_bf16(a[m], bb[cur][n], acc[m][n], 0, 0, 0);
  }

  // prefetch first W2 fragments (no Hs dependency) before the barriers
  const ushort* w2base = W2p + (size_t)(wave * 2) * 8 * 512 + lane * 8;
  bf16x8 b2b[2][2];
  #pragma unroll
  for (int n = 0; n < 2; ++n)
    b2b[0][n] = *(const bf16x8*)(w2base + (size_t)n * 8 * 512);

  // all waves must be DONE READING Xs before epilogue-1 overwrites it
  __syncthreads();

  // ---- epilogue 1: + cvec, relu, -> bf16 Hs (aliased onto Xs)
  #pragma unroll
  for (int n = 0; n < 4; ++n) {
    int col = wave * 64 + n * 16 + lr;
    #pragma unroll
    for (int m = 0; m < 4; ++m) {
      #pragma unroll
      for (int r = 0; r < 4; ++r) {
        int row = m * 16 + kg * 4 + r;
        float v = acc[m][n][r] + cv[n];
        v = v > 0.f ? v : 0.f;
        *(ushort*)(Hs + row * 512 + ((col * 2) ^ ((row & 7) << 4))) = f2b(v);
      }
    }
  }
  __syncthreads();

  // ---- GEMM2: [64x256] @ [256x32-per-wave]
  f32x4 acc2[4][2] = {};
  #pragma unroll
  for (int ks = 0; ks < 8; ++ks) {
    const int cur = ks & 1, nxt = cur ^ 1;
    if (ks < 7) {
      #pragma unroll
      for (int n = 0; n < 2; ++n)
        b2b[nxt][n] = *(const bf16x8*)(w2base + (size_t)n * 8 * 512 + (ks + 1) * 512);
    }
    const int k0 = ks * 32 + kg * 8;
    bf16x8 a[4];
    #pragma unroll
    for (int m = 0; m < 4; ++m) {
      int row = m * 16 + lr;
      a[m] = *(const bf16x8*)(Hs + row * 512 + ((k0 * 2) ^ ((row & 7) << 4)));
    }
    #pragma unroll
    for (int m = 0; m < 4; ++m)
      #pragma unroll
      for (int n = 0; n < 2; ++n)
        acc2[m][n] = __builtin_amdgcn_mfma_f32_16x16x32_bf16(a[m], b2b[cur][n], acc2[m][n], 0, 0, 0);
  }

  // ---- epilogue 2: + b2, store fp32 (wave's 64 rows x 32 cols)
  #pragma unroll
  for (int n = 0; n < 2; ++n) {
    int col = wave * 32 + n * 16 + lr;
    #pragma unroll
    for (int m = 0; m < 4; ++m) {
      #pragma unroll
      for (int r = 0; r < 4; ++r) {
        int row = m * 16 + kg * 4 + r;
        out[(size_t)(ebase + row) * D + col] = acc2[m][n][r] + bias2[n];
      }
    }
  }
}

extern "C" void kernel_launch(void* const* d_in, const int* in_sizes, int n_in,
                              void* d_out, int out_size, void* d_ws, size_t ws_size,
                              hipStream_t stream) {
  const float* edges     = (const float*)d_in[0];
  const float* nodes     = (const float*)d_in[1];
  const float* globals_  = (const float*)d_in[2];
  const int*   receivers = (const int*)d_in[3];
  const int*   senders   = (const int*)d_in[4];
  const float* W1        = (const float*)d_in[5];
  const float* b1        = (const float*)d_in[6];
  const float* W2        = (const float*)d_in[7];
  const float* b2        = (const float*)d_in[8];
  float* out = (float*)d_out;

  char* ws = (char*)d_ws;
  ushort* nodes_b = (ushort*)ws;                                // 2,560,000 B
  ushort* W1p     = (ushort*)(ws + 2560000);                    //   196,608 B
  ushort* W2p     = (ushort*)(ws + 2560000 + 196608);           //    65,536 B
  float*  cvec    = (float*)(ws + 2560000 + 196608 + 65536);    //     1,024 B

  hipLaunchKernelGGL(cast_nodes_kernel, dim3(NNODES * D / 1024), dim3(256), 0, stream,
                     nodes, nodes_b);
  hipLaunchKernelGGL(pack_w1_kernel, dim3(48), dim3(256), 0, stream, W1, W1p);
  hipLaunchKernelGGL(pack_w2_kernel, dim3(16), dim3(256), 0, stream, W2, W2p);
  hipLaunchKernelGGL(cvec_kernel, dim3(1), dim3(256), 0, stream,
                     W1, b1, globals_, cvec);
  hipLaunchKernelGGL(fused_kernel, dim3(E_TOTAL / BM), dim3(256), 0, stream,
                     edges, nodes_b, receivers, senders, W1p, cvec, W2p, b2, out);
}

// Round 15
// 146.729 us; speedup vs baseline: 1.0440x; 1.0440x over previous
//
#include <hip/hip_runtime.h>
#include <hip/hip_bf16.h>

#define D 128
#define NH 256
#define BM 64
#define E_TOTAL 320000
#define NNODES 10000

typedef __attribute__((ext_vector_type(8))) short bf16x8;
typedef __attribute__((ext_vector_type(4))) float f32x4;

__device__ __forceinline__ unsigned short f2b(float f) {
  unsigned int u = __builtin_bit_cast(unsigned int, f);
  u += 0x7fffu + ((u >> 16) & 1u);   // round-to-nearest-even
  return (unsigned short)(u >> 16);
}
__device__ __forceinline__ unsigned pk2(float a, float b) {
  return (unsigned)f2b(a) | ((unsigned)f2b(b) << 16);
}
__device__ __forceinline__ uint4 pack8(float4 a, float4 b) {
  uint4 r;
  r.x = pk2(a.x, a.y); r.y = pk2(a.z, a.w);
  r.z = pk2(b.x, b.y); r.w = pk2(b.z, b.w);
  return r;
}
__device__ __forceinline__ float lo2f(unsigned u) {
  return __builtin_bit_cast(float, u << 16);
}
__device__ __forceinline__ float hi2f(unsigned u) {
  return __builtin_bit_cast(float, u & 0xffff0000u);
}

// Pack W1 rows [0:384) into MFMA-fragment order, 3 sections of K=128:
// section s (0: edges, 1: recv, 2: send), chunk = s*4096 + nt*256 + ks*64 + l
// lane l holds W1[s*128 + ks*32 + (l>>4)*8 + j][nt*16 + (l&15)]
__global__ void pack_w1_kernel(const float* __restrict__ W1,
                               ushort* __restrict__ W1pk) {
  int c = blockIdx.x * 256 + threadIdx.x;   // 12288 threads
  int s = c >> 12;
  int rem = c & 4095;
  int nt = rem >> 8;
  int rem2 = rem & 255;
  int ks = rem2 >> 6;
  int l = rem2 & 63;
  int col = nt * 16 + (l & 15);
  int k0 = s * 128 + ks * 32 + (l >> 4) * 8;
  ushort* dst = W1pk + (size_t)c * 8;
  #pragma unroll
  for (int j = 0; j < 8; ++j)
    dst[j] = f2b(W1[(size_t)(k0 + j) * NH + col]);
}

// Pack W2 (fp32 [256][128]) fragment order: chunk c = nt2*8 + ks
__global__ void pack_w2_kernel(const float* __restrict__ W2,
                               ushort* __restrict__ W2p) {
  int c = blockIdx.x * 256 + threadIdx.x;   // 4096 threads
  int nt2 = c / (8 * 64);
  int rem = c % (8 * 64);
  int ks = rem >> 6;
  int l = rem & 63;
  int col = nt2 * 16 + (l & 15);
  int k0 = ks * 32 + (l >> 4) * 8;
  ushort* dst = W2p + (size_t)c * 8;
  #pragma unroll
  for (int j = 0; j < 8; ++j)
    dst[j] = f2b(W2[(size_t)(k0 + j) * D + col]);
}

// cvec[n] = b1[n] + sum_k globals[k] * W1[384+k][n]
__global__ void cvec_kernel(const float* __restrict__ W1,
                            const float* __restrict__ b1,
                            const float* __restrict__ g,
                            float* __restrict__ cvec) {
  int n = threadIdx.x;  // 256
  float acc = b1[n];
  for (int k = 0; k < D; ++k)
    acc += g[k] * W1[(size_t)(384 + k) * NH + n];
  cvec[n] = acc;
}

// Per-node partial products: tbl[n][h] = sum_k nodes[n][k] * W1[role*128+128+k][h]
// Swapped-orientation MFMA GEMM, K=128, bf16 output tables (role 0=recv, 1=send).
__global__ __launch_bounds__(512, 4) void nodeh_kernel(
    const float* __restrict__ nodes,
    const ushort* __restrict__ W1pk,
    ushort* __restrict__ tblR,
    ushort* __restrict__ tblS) {
  __shared__ char Xn[BM * 256];
  const int role = blockIdx.y;
  ushort* __restrict__ tbl = role ? tblS : tblR;
  const int nb = blockIdx.x * BM;
  const int tid = threadIdx.x;

  // stage 64 node rows (clamped) as bf16, swizzled
  {
    int row = tid >> 4;
    int cc = (tid & 15) * 16;
    #pragma unroll
    for (int q = 0; q < 2; ++q) {
      int r = row + q * 32;
      int rg = nb + r; if (rg >= NNODES) rg = NNODES - 1;
      const float* np = nodes + (size_t)rg * D + (tid & 15) * 8;
      float4 u0 = *(const float4*)np;
      float4 u1 = *(const float4*)(np + 4);
      *(uint4*)(Xn + r * 256 + (cc ^ ((r & 7) << 4))) = pack8(u0, u1);
    }
  }
  __syncthreads();

  const int lane = tid & 63;
  const int wave = tid >> 6;
  const int lr = lane & 15;
  const int kg = lane >> 4;

  const ushort* wb = W1pk + (size_t)(1 + role) * 32768
                   + (size_t)(wave * 2) * 2048 + lane * 8;
  f32x4 acc[2][4] = {};
  bf16x8 aw[2][2];
  #pragma unroll
  for (int ht = 0; ht < 2; ++ht)
    aw[0][ht] = *(const bf16x8*)(wb + ht * 2048);

  #pragma unroll
  for (int ks = 0; ks < 4; ++ks) {
    const int cur = ks & 1, nxt = cur ^ 1;
    if (ks < 3) {
      #pragma unroll
      for (int ht = 0; ht < 2; ++ht)
        aw[nxt][ht] = *(const bf16x8*)(wb + ht * 2048 + (ks + 1) * 512);
    }
    const int k0 = ks * 32 + kg * 8;
    bf16x8 xb[4];
    #pragma unroll
    for (int et = 0; et < 4; ++et) {
      int row = et * 16 + lr;
      xb[et] = *(const bf16x8*)(Xn + row * 256 + ((k0 * 2) ^ ((row & 7) << 4)));
    }
    #pragma unroll
    for (int ht = 0; ht < 2; ++ht)
      #pragma unroll
      for (int et = 0; et < 4; ++et)
        acc[ht][et] = __builtin_amdgcn_mfma_f32_16x16x32_bf16(aw[cur][ht], xb[et], acc[ht][et], 0, 0, 0);
  }

  #pragma unroll
  for (int ht = 0; ht < 2; ++ht) {
    int h0 = wave * 32 + ht * 16 + kg * 4;
    #pragma unroll
    for (int et = 0; et < 4; ++et) {
      int n = nb + et * 16 + lr;
      if (n < NNODES) {
        uint2 pk;
        pk.x = pk2(acc[ht][et][0], acc[ht][et][1]);
        pk.y = pk2(acc[ht][et][2], acc[ht][et][3]);
        *(uint2*)(tbl + (size_t)n * NH + h0) = pk;
      }
    }
  }
}

// Fused edge kernel: H = relu(edges@W1a + Hpre), Hpre = nodeHr[r]+nodeHs[s]+cvec
// staged coalesced into LDS; GEMM1 K=128 (swapped orientation, r8-verified);
// epilogue-1 updates Hpre IN PLACE (lane-private b64 positions) -> Hs;
// GEMM2 = r8 verbatim. LDS 48 KB.
__global__ __launch_bounds__(512, 4) void fused_kernel(
    const float* __restrict__ edges,
    const int* __restrict__ receivers,
    const int* __restrict__ senders,
    const ushort* __restrict__ W1pk,   // section 0 = edges K=128
    const ushort* __restrict__ tblR,
    const ushort* __restrict__ tblS,
    const float* __restrict__ cvec,
    const ushort* __restrict__ W2p,
    const float* __restrict__ b2,
    float* __restrict__ out) {
  __shared__ char Xs[BM * 256];   // edges bf16, swz byte ^= (row&7)<<4
  __shared__ char Hp[BM * 512];   // Hpre -> Hs (in place), same swizzle

  const int ebase = blockIdx.x * BM;
  const int tid = threadIdx.x;

  // ---- gather indices (4 edges per thread)
  const int ge = tid >> 5;            // 0..15
  const int gc0 = (tid & 31) * 8;     // hidden-col chunk 0..248
  int idxR[4], idxS[4];
  #pragma unroll
  for (int j = 0; j < 4; ++j) {
    idxR[j] = receivers[ebase + ge + j * 16];
    idxS[j] = senders[ebase + ge + j * 16];
  }

  // ---- edge loads (rows erow, erow+32; 8 f32 each)
  const int erow = tid >> 4;
  const int ecc = (tid & 15) * 16;
  float4 e0, e1, e2, e3;
  {
    const float* ep0 = edges + (size_t)(ebase + erow) * D + (tid & 15) * 8;
    e0 = *(const float4*)ep0;
    e1 = *(const float4*)(ep0 + 4);
    const float* ep1 = edges + (size_t)(ebase + erow + 32) * D + (tid & 15) * 8;
    e2 = *(const float4*)ep1;
    e3 = *(const float4*)(ep1 + 4);
  }

  // ---- cvec for this thread's fixed col chunk
  float4 cva = *(const float4*)(cvec + gc0);
  float4 cvb = *(const float4*)(cvec + gc0 + 4);

  // ---- nodeH gathers (coalesced 16B; 2 x 512B segments per wave-instr)
  uint4 gR[4], gS[4];
  #pragma unroll
  for (int j = 0; j < 4; ++j) {
    gR[j] = *(const uint4*)(tblR + (size_t)idxR[j] * NH + gc0);
    gS[j] = *(const uint4*)(tblS + (size_t)idxS[j] * NH + gc0);
  }

  // ---- write edges to Xs
  *(uint4*)(Xs + erow * 256 + (ecc ^ ((erow & 7) << 4))) = pack8(e0, e1);
  {
    int r2 = erow + 32;
    *(uint4*)(Xs + r2 * 256 + (ecc ^ ((r2 & 7) << 4))) = pack8(e2, e3);
  }

  // ---- sum nodeHr + nodeHs + cvec -> Hpre (bf16)
  #pragma unroll
  for (int j = 0; j < 4; ++j) {
    int e = ge + j * 16;
    float s0 = lo2f(gR[j].x) + lo2f(gS[j].x) + cva.x;
    float s1 = hi2f(gR[j].x) + hi2f(gS[j].x) + cva.y;
    float s2 = lo2f(gR[j].y) + lo2f(gS[j].y) + cva.z;
    float s3 = hi2f(gR[j].y) + hi2f(gS[j].y) + cva.w;
    float s4 = lo2f(gR[j].z) + lo2f(gS[j].z) + cvb.x;
    float s5 = hi2f(gR[j].z) + hi2f(gS[j].z) + cvb.y;
    float s6 = lo2f(gR[j].w) + lo2f(gS[j].w) + cvb.z;
    float s7 = hi2f(gR[j].w) + hi2f(gS[j].w) + cvb.w;
    uint4 o;
    o.x = pk2(s0, s1); o.y = pk2(s2, s3);
    o.z = pk2(s4, s5); o.w = pk2(s6, s7);
    *(uint4*)(Hp + e * 512 + ((gc0 * 2) ^ ((e & 7) << 4))) = o;
  }
  __syncthreads();

  const int lane = tid & 63;
  const int wave = tid >> 6;     // GEMM1: hidden cols [32w, 32w+32)
  const int lr = lane & 15;
  const int kg = lane >> 4;
  const int wm3 = wave >> 1;     // GEMM2: out cols [32*wm3, ...)
  const int wn3 = wave & 1;      //        edges    [32*wn3, ...)

  // ---- GEMM1 (swapped, K=128): H^T[32h x 64e] += W1a^T-frag * X-row-frag
  const ushort* w1base = W1pk + (size_t)(wave * 2) * 2048 + lane * 8;
  f32x4 acc[2][4] = {};
  bf16x8 aw[2][2];
  #pragma unroll
  for (int ht = 0; ht < 2; ++ht)
    aw[0][ht] = *(const bf16x8*)(w1base + ht * 2048);

  #pragma unroll
  for (int ks = 0; ks < 4; ++ks) {
    const int cur = ks & 1, nxt = cur ^ 1;
    if (ks < 3) {
      #pragma unroll
      for (int ht = 0; ht < 2; ++ht)
        aw[nxt][ht] = *(const bf16x8*)(w1base + ht * 2048 + (ks + 1) * 512);
    }
    const int k0 = ks * 32 + kg * 8;
    bf16x8 xb[4];
    #pragma unroll
    for (int et = 0; et < 4; ++et) {
      int row = et * 16 + lr;
      xb[et] = *(const bf16x8*)(Xs + row * 256 + ((k0 * 2) ^ ((row & 7) << 4)));
    }
    #pragma unroll
    for (int ht = 0; ht < 2; ++ht)
      #pragma unroll
      for (int et = 0; et < 4; ++et)
        acc[ht][et] = __builtin_amdgcn_mfma_f32_16x16x32_bf16(aw[cur][ht], xb[et], acc[ht][et], 0, 0, 0);
  }

  // prefetch first W2^T fragments before the barrier
  const ushort* w2base = W2p + (size_t)(wm3 * 2) * 8 * 512 + lane * 8;
  bf16x8 aw2[2][2];
  #pragma unroll
  for (int mt = 0; mt < 2; ++mt)
    aw2[0][mt] = *(const bf16x8*)(w2base + (size_t)mt * 8 * 512);

  // ---- epilogue 1: in-place H = relu(acc + Hpre), lane-private b64 positions
  #pragma unroll
  for (int ht = 0; ht < 2; ++ht) {
    const int h0b = (wave * 32 + ht * 16 + kg * 4) * 2;
    #pragma unroll
    for (int et = 0; et < 4; ++et) {
      int e = et * 16 + lr;
      char* p = Hp + e * 512 + (h0b ^ ((e & 7) << 4));
      uint2 hp = *(uint2*)p;
      float v0 = acc[ht][et][0] + lo2f(hp.x);
      float v1 = acc[ht][et][1] + hi2f(hp.x);
      float v2 = acc[ht][et][2] + lo2f(hp.y);
      float v3 = acc[ht][et][3] + hi2f(hp.y);
      v0 = v0 > 0.f ? v0 : 0.f;
      v1 = v1 > 0.f ? v1 : 0.f;
      v2 = v2 > 0.f ? v2 : 0.f;
      v3 = v3 > 0.f ? v3 : 0.f;
      uint2 pk;
      pk.x = pk2(v0, v1);
      pk.y = pk2(v2, v3);
      *(uint2*)p = pk;
    }
  }
  __syncthreads();

  // ---- GEMM2 (swapped, r8-verified): out^T[32c x 32e] += W2^T-frag * H-row-frag
  float4 ba = *(const float4*)(b2 + wm3 * 32 + kg * 4);
  float4 bb2 = *(const float4*)(b2 + wm3 * 32 + 16 + kg * 4);
  f32x4 acc2[2][2] = {};
  #pragma unroll
  for (int ks = 0; ks < 8; ++ks) {
    const int cur = ks & 1, nxt = cur ^ 1;
    if (ks < 7) {
      #pragma unroll
      for (int mt = 0; mt < 2; ++mt)
        aw2[nxt][mt] = *(const bf16x8*)(w2base + (size_t)mt * 8 * 512 + (ks + 1) * 512);
    }
    const int k0 = ks * 32 + kg * 8;
    bf16x8 hb[2];
    #pragma unroll
    for (int et2 = 0; et2 < 2; ++et2) {
      int e = wn3 * 32 + et2 * 16 + lr;
      hb[et2] = *(const bf16x8*)(Hp + e * 512 + ((k0 * 2) ^ ((e & 7) << 4)));
    }
    #pragma unroll
    for (int mt = 0; mt < 2; ++mt)
      #pragma unroll
      for (int et2 = 0; et2 < 2; ++et2)
        acc2[mt][et2] = __builtin_amdgcn_mfma_f32_16x16x32_bf16(aw2[cur][mt], hb[et2], acc2[mt][et2], 0, 0, 0);
  }

  // ---- epilogue 2: + b2, float4 stores (4 consecutive out cols of one edge)
  #pragma unroll
  for (int mt = 0; mt < 2; ++mt) {
    const float4 bq = mt ? bb2 : ba;
    const int c0 = wm3 * 32 + mt * 16 + kg * 4;
    #pragma unroll
    for (int et2 = 0; et2 < 2; ++et2) {
      int e = wn3 * 32 + et2 * 16 + lr;
      float4 o;
      o.x = acc2[mt][et2][0] + bq.x;
      o.y = acc2[mt][et2][1] + bq.y;
      o.z = acc2[mt][et2][2] + bq.z;
      o.w = acc2[mt][et2][3] + bq.w;
      *(float4*)(out + (size_t)(ebase + e) * D + c0) = o;
    }
  }
}

extern "C" void kernel_launch(void* const* d_in, const int* in_sizes, int n_in,
                              void* d_out, int out_size, void* d_ws, size_t ws_size,
                              hipStream_t stream) {
  const float* edges     = (const float*)d_in[0];
  const float* nodes     = (const float*)d_in[1];
  const float* globals_  = (const float*)d_in[2];
  const int*   receivers = (const int*)d_in[3];
  const int*   senders   = (const int*)d_in[4];
  const float* W1        = (const float*)d_in[5];
  const float* b1        = (const float*)d_in[6];
  const float* W2        = (const float*)d_in[7];
  const float* b2        = (const float*)d_in[8];
  float* out = (float*)d_out;

  char* ws = (char*)d_ws;
  ushort* W1pk = (ushort*)ws;                       //   196,608 B
  ushort* W2p  = (ushort*)(ws + 196608);            //    65,536 B
  float*  cvec = (float*)(ws + 262144);             //     1,024 B
  ushort* tblR = (ushort*)(ws + 263168);            // 5,120,000 B
  ushort* tblS = (ushort*)(ws + 5383168);           // 5,120,000 B

  hipLaunchKernelGGL(pack_w1_kernel, dim3(48), dim3(256), 0, stream, W1, W1pk);
  hipLaunchKernelGGL(pack_w2_kernel, dim3(16), dim3(256), 0, stream, W2, W2p);
  hipLaunchKernelGGL(cvec_kernel, dim3(1), dim3(256), 0, stream,
                     W1, b1, globals_, cvec);
  hipLaunchKernelGGL(nodeh_kernel, dim3((NNODES + BM - 1) / BM, 2), dim3(512), 0, stream,
                     nodes, W1pk, tblR, tblS);
  hipLaunchKernelGGL(fused_kernel, dim3(E_TOTAL / BM), dim3(512), 0, stream,
                     edges, receivers, senders, W1pk, tblR, tblS, cvec, W2p, b2, out);
}